// Round 11
// baseline (35.514 us; speedup 1.0000x reference)
//
#include <hip/hip_runtime.h>
#include <math.h>

#define BATCH 512
#define CCH   64
#define NND   32
#define VOC   100
#define DEMB  32
#define HID   64
#define NEDGE 256
#define NT    37

// Batch-invariant precompute lives in ordinary __device__ globals (L2-cached
// VRAM). r6 evidence: d_ws is fine-grained/uncached (4B lane loads -> full
// 64B line HBM fetches, 212MB); __device__ arrays don't have that problem.
__device__ float gT[2 * CCH * VOC * HID];   // T[g][c][v][o] = emb[c,v,:] @ (W_g @ L_g[:64])
__device__ float gA[NND * NND];             // dense normalized adjacency (row=dst)
__device__ float gCB[2 * HID];              // b_g @ L_g[:64] + lb_g
__device__ float gPC[NT + 1];               // softmax(att) prefix sums

// ---------------- prep: grid 64 (one block per channel c), 512 threads ----
__global__ __launch_bounds__(512)
void a3_prep(const int* __restrict__ tei, const float* __restrict__ att,
             const float* __restrict__ emb,
             const float* __restrict__ Wz, const float* __restrict__ bz,
             const float* __restrict__ Wh, const float* __restrict__ bh,
             const float* __restrict__ Lz, const float* __restrict__ lbz,
             const float* __restrict__ Lh, const float* __restrict__ lbh) {
    __shared__ float sWL[2][DEMB][HID];     // 16 KB
    __shared__ int   sdeg[NND];
    __shared__ float sdinv[NND];
    __shared__ float lA[NND][NND];

    const int tid = threadIdx.x;
    const int o   = tid & 63;
    const int wv  = tid >> 6;               // 0..7
    const int c   = blockIdx.x;

    // WL[g][k][o] = sum_m W_g[k][m] * L_g[m][o]   (k = wv+8i; i<4 -> g=0, i>=4 -> g=1)
    {
        float az[4], ah[4];
#pragma unroll
        for (int i = 0; i < 4; ++i) { az[i] = 0.f; ah[i] = 0.f; }
        for (int m = 0; m < HID; ++m) {
            const float lz = Lz[m * HID + o];
            const float lh = Lh[m * HID + o];
#pragma unroll
            for (int i = 0; i < 4; ++i) {
                const int k = wv + 8 * i;
                az[i] = fmaf(Wz[k * HID + m], lz, az[i]);
                ah[i] = fmaf(Wh[k * HID + m], lh, ah[i]);
            }
        }
#pragma unroll
        for (int i = 0; i < 4; ++i) {
            sWL[0][wv + 8 * i][o] = az[i];
            sWL[1][wv + 8 * i][o] = ah[i];
        }
    }
    __syncthreads();

    // T[g][c][v][o] = sum_k emb[c][v][k] * WL[g][k][o]
    for (int vi = 0; vi < 13; ++vi) {
        const int v = wv + 8 * vi;
        if (v < VOC) {
            float tz = 0.f, th = 0.f;
            for (int k = 0; k < DEMB; ++k) {
                const float e = emb[(c * VOC + v) * DEMB + k];   // wave-uniform
                tz = fmaf(e, sWL[0][k][o], tz);
                th = fmaf(e, sWL[1][k][o], th);
            }
            gT[((0 * CCH + c) * VOC + v) * HID + o] = tz;
            gT[((1 * CCH + c) * VOC + v) * HID + o] = th;
        }
    }

    // block 0: adjacency, cb, softmax prefix (barriers are block-uniform here)
    if (blockIdx.x == 0) {
        if (tid < NND) sdeg[tid] = 1;                    // self-loop
#pragma unroll
        for (int i = 0; i < 2; ++i) ((float*)lA)[tid + 512 * i] = 0.f;
        __syncthreads();
        int se = 0, de = 0;
        if (tid < NEDGE) {
            se = tei[tid]; de = tei[NEDGE + tid];
            atomicAdd(&sdeg[de], 1);
        }
        __syncthreads();
        if (tid < NND) sdinv[tid] = rsqrtf((float)sdeg[tid]);
        __syncthreads();
        if (tid < NEDGE) atomicAdd(&lA[de][se], sdinv[se] * sdinv[de]);
        if (tid < NND)   atomicAdd(&lA[tid][tid], sdinv[tid] * sdinv[tid]);
        __syncthreads();
#pragma unroll
        for (int i = 0; i < 2; ++i) gA[tid + 512 * i] = ((float*)lA)[tid + 512 * i];

        if (tid < 2 * HID) {                             // cb = b@L[:64] + lb
            const int g = tid >> 6, cc = tid & 63;
            const float* Lg  = g ? Lh  : Lz;
            const float* bg  = g ? bh  : bz;
            const float* lbg = g ? lbh : lbz;
            float s = lbg[cc];
            for (int k = 0; k < HID; ++k) s = fmaf(bg[k], Lg[k * HID + cc], s);
            gCB[tid] = s;
        }
        if (tid <= NT) {                                 // softmax prefix
            float m = att[0];
            for (int t = 1; t < NT; ++t) m = fmaxf(m, att[t]);
            float tot = 0.f, pre = 0.f;
            for (int t = 0; t < NT; ++t) {
                const float e = __expf(att[t] - m);
                tot += e;
                if (t < tid) pre += e;
            }
            gPC[tid] = pre / tot;
        }
    }
}

// ---------------- main: grid 512 (one block per batch), 512 threads ----------
__global__ __launch_bounds__(512, 4)
void a3_main(const int* __restrict__ xbg, const int* __restrict__ LOSb,
             const float* __restrict__ Wc1, const float* __restrict__ bc1,
             const float* __restrict__ Wc2, const float* __restrict__ bc2,
             float* __restrict__ out) {
    __shared__ float sA[NND][NND];          // 4 KB (broadcast reads only)
    __shared__ int   srb[2][CCH];           // gT row base per (gate, channel)
    __shared__ float scb[2][HID];
    __shared__ float part[8][HID];          // 2 KB
    __shared__ float pooled[HID];
    __shared__ float h1s[2 * HID];

    const int b   = blockIdx.x;
    const int tid = threadIdx.x;
    const int hd  = tid & 63;
    const int wv  = tid >> 6;               // 0..7

    // ---- stage: adjacency + row-base LUT + cb ----
#pragma unroll
    for (int i = 0; i < 2; ++i) ((float*)sA)[tid + 512 * i] = gA[tid + 512 * i];
    if (tid < CCH) {
        const int xbv = xbg[b * CCH + tid];
        srb[0][tid] = ((0 * CCH + tid) * VOC + xbv) * HID;
        srb[1][tid] = ((1 * CCH + tid) * VOC + xbv) * HID;
    }
    if (tid < 2 * HID) ((float*)scb)[tid] = gCB[tid];
    const float cA = gPC[LOSb[b]];
    const float cD = 1.0f - cA;
    __syncthreads();

    // ---- gates: wave wv owns 8 rows of variant var; reads gT direct ----
    const int var = wv >> 2;                // waves 0-3: ad, 4-7: dis
    const int n0  = (wv & 3) * 8;
    float zacc[8], hacc[8];
#pragma unroll
    for (int j = 0; j < 8; ++j) { zacc[j] = 0.f; hacc[j] = 0.f; }
    for (int q = 0; q < NND; ++q) {
        const int cc = var * NND + q;
        const float tz = gT[srb[0][cc] + hd];   // coalesced, L1/L2-hot
        const float th = gT[srb[1][cc] + hd];
#pragma unroll
        for (int j = 0; j < 8; ++j) {
            const float a = sA[n0 + j][q];      // wave-uniform broadcast
            zacc[j] = fmaf(a, tz, zacc[j]);
            hacc[j] = fmaf(a, th, hacc[j]);
        }
    }
    const float wr = var ? cD : cA;
    float psum = 0.f;
#pragma unroll
    for (int j = 0; j < 8; ++j) {
        const float zl = zacc[j] + scb[0][hd];
        const float hl = hacc[j] + scb[1][hd];
        const float Z  = 1.0f / (1.0f + __expf(-zl));
        const float e2 = __expf(2.0f * hl);
        const float Ht = (e2 - 1.0f) / (e2 + 1.0f);
        psum = fmaf(1.0f - Z, Ht, psum);        // sum of cells; weight applied below
    }
    part[wv][hd] = wr * psum;
    __syncthreads();

    // ---- pool over nodes ----
    if (tid < HID) {
        float s = 0.f;
#pragma unroll
        for (int g = 0; g < 8; ++g) s += part[g][tid];
        pooled[tid] = s * (1.0f / NND);
    }
    __syncthreads();

    // ---- head ----
    if (tid < 2 * HID) {
        float a = bc1[tid];
#pragma unroll 4
        for (int k = 0; k < HID; ++k) a = fmaf(pooled[k], Wc1[k * 2 * HID + tid], a);
        h1s[tid] = fmaxf(a, 0.f) * Wc2[tid];
    }
    __syncthreads();
    if (tid < 64) {
        float v = h1s[tid] + h1s[tid + 64];
#pragma unroll
        for (int off = 32; off; off >>= 1) v += __shfl_down(v, off);
        if (tid == 0) out[b] = v + bc2[0];
    }
}

extern "C" void kernel_launch(void* const* d_in, const int* in_sizes, int n_in,
                              void* d_out, int out_size, void* d_ws, size_t ws_size,
                              hipStream_t stream) {
    const int*   x_batch = (const int*)d_in[0];
    const int*   LOSb    = (const int*)d_in[1];
    const int*   tei     = (const int*)d_in[2];
    const float* emb     = (const float*)d_in[3];
    const float* Wz      = (const float*)d_in[4];
    const float* bz      = (const float*)d_in[5];
    const float* Wh      = (const float*)d_in[8];
    const float* bh      = (const float*)d_in[9];
    const float* Lz      = (const float*)d_in[10];
    const float* lbz     = (const float*)d_in[11];
    const float* Lh      = (const float*)d_in[14];
    const float* lbh     = (const float*)d_in[15];
    const float* att     = (const float*)d_in[16];
    const float* Wc1     = (const float*)d_in[17];
    const float* bc1     = (const float*)d_in[18];
    const float* Wc2     = (const float*)d_in[19];
    const float* bc2     = (const float*)d_in[20];
    float* outp = (float*)d_out;

    hipLaunchKernelGGL(a3_prep, dim3(CCH), dim3(512), 0, stream,
                       tei, att, emb, Wz, bz, Wh, bh, Lz, lbz, Lh, lbh);
    hipLaunchKernelGGL(a3_main, dim3(BATCH), dim3(512), 0, stream,
                       x_batch, LOSb, Wc1, bc1, Wc2, bc2, outp);
}

// Round 12
// 33.371 us; speedup vs baseline: 1.0642x; 1.0642x over previous
//
#include <hip/hip_runtime.h>
#include <math.h>

#define BATCH 512
#define CCH   64
#define NND   32
#define VOC   100
#define DEMB  32
#define HID   64
#define NEDGE 256
#define NT    37

// Precomputed batch-invariant tables in ordinary __device__ globals (L2-cached).
// gT2[(c*VOC+v)*HID + o] = {emb[c,v,:] @ (Wz@Lz[:64]) , emb[c,v,:] @ (Wh@Lh[:64])}[o]
__device__ float2 gT2[CCH * VOC * HID];     // 3.27 MB
__device__ float  gA[NND * NND];            // dense normalized adjacency (row=dst)
__device__ float  gCB[2 * HID];             // b_g @ L_g[:64] + lb_g
__device__ float  gPC[NT + 1];              // softmax(att) prefix sums

// ---- prep: grid 256 = 64 channels x 4 vocab-groups, 512 threads -------------
__global__ __launch_bounds__(512)
void a3_prep(const int* __restrict__ tei, const float* __restrict__ att,
             const float* __restrict__ emb,
             const float* __restrict__ Wz, const float* __restrict__ bz,
             const float* __restrict__ Wh, const float* __restrict__ bh,
             const float* __restrict__ Lz, const float* __restrict__ lbz,
             const float* __restrict__ Lh, const float* __restrict__ lbh) {
    __shared__ float sWL[2][DEMB][HID];     // 16 KB
    __shared__ int   sdeg[NND];
    __shared__ float sdinv[NND];
    __shared__ float lA[NND][NND];

    const int tid = threadIdx.x;
    const int o   = tid & 63;
    const int wv  = tid >> 6;               // 0..7
    const int c   = blockIdx.x >> 2;
    const int vg  = blockIdx.x & 3;         // vocab group: 25 entries each

    // WL[g][k][o] = sum_m W_g[k][m] * L_g[m][o]  (k = wv + 8i)
    {
        float az[4], ah[4];
#pragma unroll
        for (int i = 0; i < 4; ++i) { az[i] = 0.f; ah[i] = 0.f; }
        for (int m = 0; m < HID; ++m) {
            const float lz = Lz[m * HID + o];
            const float lh = Lh[m * HID + o];
#pragma unroll
            for (int i = 0; i < 4; ++i) {
                const int k = wv + 8 * i;
                az[i] = fmaf(Wz[k * HID + m], lz, az[i]);
                ah[i] = fmaf(Wh[k * HID + m], lh, ah[i]);
            }
        }
#pragma unroll
        for (int i = 0; i < 4; ++i) {
            sWL[0][wv + 8 * i][o] = az[i];
            sWL[1][wv + 8 * i][o] = ah[i];
        }
    }
    __syncthreads();

    // T for 25 vocab entries of this group
#pragma unroll
    for (int vi = 0; vi < 4; ++vi) {
        const int vl = wv + 8 * vi;         // 0..31
        if (vl < 25) {
            const int v = vg * 25 + vl;
            float tz = 0.f, th = 0.f;
            for (int k = 0; k < DEMB; ++k) {
                const float e = emb[(c * VOC + v) * DEMB + k];   // wave-uniform
                tz = fmaf(e, sWL[0][k][o], tz);
                th = fmaf(e, sWL[1][k][o], th);
            }
            gT2[(c * VOC + v) * HID + o] = make_float2(tz, th);
        }
    }

    // block 0: adjacency, cb, softmax prefix
    if (blockIdx.x == 0) {
        if (tid < NND) sdeg[tid] = 1;                    // self-loop
#pragma unroll
        for (int i = 0; i < 2; ++i) ((float*)lA)[tid + 512 * i] = 0.f;
        __syncthreads();
        int se = 0, de = 0;
        if (tid < NEDGE) {
            se = tei[tid]; de = tei[NEDGE + tid];
            atomicAdd(&sdeg[de], 1);
        }
        __syncthreads();
        if (tid < NND) sdinv[tid] = rsqrtf((float)sdeg[tid]);
        __syncthreads();
        if (tid < NEDGE) atomicAdd(&lA[de][se], sdinv[se] * sdinv[de]);
        if (tid < NND)   atomicAdd(&lA[tid][tid], sdinv[tid] * sdinv[tid]);
        __syncthreads();
#pragma unroll
        for (int i = 0; i < 2; ++i) gA[tid + 512 * i] = ((float*)lA)[tid + 512 * i];

        if (tid < 2 * HID) {
            const int g = tid >> 6, cc = tid & 63;
            const float* Lg  = g ? Lh  : Lz;
            const float* bg  = g ? bh  : bz;
            const float* lbg = g ? lbh : lbz;
            float s = lbg[cc];
            for (int k = 0; k < HID; ++k) s = fmaf(bg[k], Lg[k * HID + cc], s);
            gCB[tid] = s;
        }
        if (tid <= NT) {
            float m = att[0];
            for (int t = 1; t < NT; ++t) m = fmaxf(m, att[t]);
            float tot = 0.f, pre = 0.f;
            for (int t = 0; t < NT; ++t) {
                const float e = __expf(att[t] - m);
                tot += e;
                if (t < tid) pre += e;
            }
            gPC[tid] = pre / tot;
        }
    }
}

// ---- main: grid 512 (block=batch), 512 threads, 2 barriers ------------------
__global__ __launch_bounds__(512, 4)
void a3_main(const int* __restrict__ xbg, const int* __restrict__ LOSb,
             const float* __restrict__ Wc1, const float* __restrict__ bc1,
             const float* __restrict__ Wc2, const float* __restrict__ bc2,
             float* __restrict__ out) {
    __shared__ float sA[NND][NND];          // 4 KB
    __shared__ float scb[2][HID];           // 512 B
    __shared__ float part[8][HID];          // 2 KB
    __shared__ float spool[HID];

    const int b    = blockIdx.x;
    const int tid  = threadIdx.x;
    const int hd   = tid & 63;
    const int wv   = tid >> 6;              // 0..7
    const int var  = wv >> 2;               // 0: ad, 1: dis
    const int n0   = (wv & 3) * 8;

    // stage: adjacency + cb (one barrier)
#pragma unroll
    for (int i = 0; i < 2; ++i) ((float*)sA)[tid + 512 * i] = gA[tid + 512 * i];
    if (tid < 2 * HID) ((float*)scb)[tid] = gCB[tid];
    // per-lane vocab index for this wave's variant (lanes 32-63 duplicate)
    const int xv = xbg[b * CCH + var * NND + (tid & 31)];
    const float cA = gPC[LOSb[b]];
    __syncthreads();

    // gate loop: one float2 load + 16 fma per channel q
    float zacc[8], hacc[8];
#pragma unroll
    for (int j = 0; j < 8; ++j) { zacc[j] = 0.f; hacc[j] = 0.f; }
#pragma unroll 8
    for (int q = 0; q < NND; ++q) {
        const int xq = __shfl(xv, q);                       // vocab id of channel
        const int cc = var * NND + q;
        const float2 t = gT2[(cc * VOC + xq) * HID + hd];   // coalesced, L2-hot
#pragma unroll
        for (int j = 0; j < 8; ++j) {
            const float a = sA[n0 + j][q];                  // broadcast
            zacc[j] = fmaf(a, t.x, zacc[j]);
            hacc[j] = fmaf(a, t.y, hacc[j]);
        }
    }
    const float wr = var ? (1.0f - cA) : cA;
    float psum = 0.f;
#pragma unroll
    for (int j = 0; j < 8; ++j) {
        const float zl = zacc[j] + scb[0][hd];
        const float hl = hacc[j] + scb[1][hd];
        const float Z  = 1.0f / (1.0f + __expf(-zl));
        const float e2 = __expf(2.0f * hl);
        const float Ht = (e2 - 1.0f) / (e2 + 1.0f);
        psum = fmaf(1.0f - Z, Ht, psum);
    }
    part[wv][hd] = wr * psum;
    __syncthreads();                         // second (last) barrier

    // tail: wave 0 only; other waves done
    if (wv == 0) {
        float s = 0.f;
#pragma unroll
        for (int g = 0; g < 8; ++g) s += part[g][hd];
        spool[hd] = s * (1.0f / NND);        // wave-internal LDS, no barrier
        float a0 = bc1[hd], a1 = bc1[hd + 64];
#pragma unroll 8
        for (int k = 0; k < HID; ++k) {
            const float pk = spool[k];
            a0 = fmaf(pk, Wc1[k * 2 * HID + hd], a0);
            a1 = fmaf(pk, Wc1[k * 2 * HID + hd + 64], a1);
        }
        float v = fmaxf(a0, 0.f) * Wc2[hd] + fmaxf(a1, 0.f) * Wc2[hd + 64];
#pragma unroll
        for (int off = 32; off; off >>= 1) v += __shfl_down(v, off);
        if (hd == 0) out[b] = v + bc2[0];
    }
}

extern "C" void kernel_launch(void* const* d_in, const int* in_sizes, int n_in,
                              void* d_out, int out_size, void* d_ws, size_t ws_size,
                              hipStream_t stream) {
    const int*   x_batch = (const int*)d_in[0];
    const int*   LOSb    = (const int*)d_in[1];
    const int*   tei     = (const int*)d_in[2];
    const float* emb     = (const float*)d_in[3];
    const float* Wz      = (const float*)d_in[4];
    const float* bz      = (const float*)d_in[5];
    const float* Wh      = (const float*)d_in[8];
    const float* bh      = (const float*)d_in[9];
    const float* Lz      = (const float*)d_in[10];
    const float* lbz     = (const float*)d_in[11];
    const float* Lh      = (const float*)d_in[14];
    const float* lbh     = (const float*)d_in[15];
    const float* att     = (const float*)d_in[16];
    const float* Wc1     = (const float*)d_in[17];
    const float* bc1     = (const float*)d_in[18];
    const float* Wc2     = (const float*)d_in[19];
    const float* bc2     = (const float*)d_in[20];
    float* outp = (float*)d_out;

    hipLaunchKernelGGL(a3_prep, dim3(256), dim3(512), 0, stream,
                       tei, att, emb, Wz, bz, Wh, bh, Lz, lbz, Lh, lbh);
    hipLaunchKernelGGL(a3_main, dim3(BATCH), dim3(512), 0, stream,
                       x_batch, LOSb, Wc1, bc1, Wc2, bc2, outp);
}

// Round 13
// 33.252 us; speedup vs baseline: 1.0680x; 1.0036x over previous
//
#include <hip/hip_runtime.h>
#include <math.h>

#define BATCH 512
#define CCH   64
#define NND   32
#define VOC   100
#define DEMB  32
#define HID   64
#define NEDGE 256
#define NT    37

// Precomputed batch-invariant tables in ordinary __device__ globals (L2-cached).
// gT2[(c*VOC+v)*HID + o] = {emb[c,v,:] @ (Wz@Lz[:64]) , emb[c,v,:] @ (Wh@Lh[:64])}[o]
__device__ float2 gT2[CCH * VOC * HID];     // 3.27 MB
__device__ float  gA[NND * NND];            // dense normalized adjacency (row=dst)
__device__ float  gCB[2 * HID];             // b_g @ L_g[:64] + lb_g
__device__ float  gPC[NT + 1];              // softmax(att) prefix sums

// ---- prep: grid 256 = 64 channels x 4 vocab-groups, 512 threads -------------
__global__ __launch_bounds__(512)
void a3_prep(const int* __restrict__ tei, const float* __restrict__ att,
             const float* __restrict__ emb,
             const float* __restrict__ Wz, const float* __restrict__ bz,
             const float* __restrict__ Wh, const float* __restrict__ bh,
             const float* __restrict__ Lz, const float* __restrict__ lbz,
             const float* __restrict__ Lh, const float* __restrict__ lbh) {
    __shared__ float sWL[2][DEMB][HID];     // 16 KB
    __shared__ int   sdeg[NND];
    __shared__ float sdinv[NND];
    __shared__ float lA[NND][NND];

    const int tid = threadIdx.x;
    const int o   = tid & 63;
    const int wv  = tid >> 6;               // 0..7
    const int c   = blockIdx.x >> 2;
    const int vg  = blockIdx.x & 3;         // vocab group: 25 entries each

    // WL[g][k][o] = sum_m W_g[k][m] * L_g[m][o]  (k = wv + 8i)
    {
        float az[4], ah[4];
#pragma unroll
        for (int i = 0; i < 4; ++i) { az[i] = 0.f; ah[i] = 0.f; }
        for (int m = 0; m < HID; ++m) {
            const float lz = Lz[m * HID + o];
            const float lh = Lh[m * HID + o];
#pragma unroll
            for (int i = 0; i < 4; ++i) {
                const int k = wv + 8 * i;
                az[i] = fmaf(Wz[k * HID + m], lz, az[i]);
                ah[i] = fmaf(Wh[k * HID + m], lh, ah[i]);
            }
        }
#pragma unroll
        for (int i = 0; i < 4; ++i) {
            sWL[0][wv + 8 * i][o] = az[i];
            sWL[1][wv + 8 * i][o] = ah[i];
        }
    }
    __syncthreads();

    // T for 25 vocab entries of this group
#pragma unroll
    for (int vi = 0; vi < 4; ++vi) {
        const int vl = wv + 8 * vi;         // 0..31
        if (vl < 25) {
            const int v = vg * 25 + vl;
            float tz = 0.f, th = 0.f;
            for (int k = 0; k < DEMB; ++k) {
                const float e = emb[(c * VOC + v) * DEMB + k];   // wave-uniform
                tz = fmaf(e, sWL[0][k][o], tz);
                th = fmaf(e, sWL[1][k][o], th);
            }
            gT2[(c * VOC + v) * HID + o] = make_float2(tz, th);
        }
    }

    // block 0: adjacency, cb, softmax prefix
    if (blockIdx.x == 0) {
        if (tid < NND) sdeg[tid] = 1;                    // self-loop
#pragma unroll
        for (int i = 0; i < 2; ++i) ((float*)lA)[tid + 512 * i] = 0.f;
        __syncthreads();
        int se = 0, de = 0;
        if (tid < NEDGE) {
            se = tei[tid]; de = tei[NEDGE + tid];
            atomicAdd(&sdeg[de], 1);
        }
        __syncthreads();
        if (tid < NND) sdinv[tid] = rsqrtf((float)sdeg[tid]);
        __syncthreads();
        if (tid < NEDGE) atomicAdd(&lA[de][se], sdinv[se] * sdinv[de]);
        if (tid < NND)   atomicAdd(&lA[tid][tid], sdinv[tid] * sdinv[tid]);
        __syncthreads();
#pragma unroll
        for (int i = 0; i < 2; ++i) gA[tid + 512 * i] = ((float*)lA)[tid + 512 * i];

        if (tid < 2 * HID) {
            const int g = tid >> 6, cc = tid & 63;
            const float* Lg  = g ? Lh  : Lz;
            const float* bg  = g ? bh  : bz;
            const float* lbg = g ? lbh : lbz;
            float s = lbg[cc];
            for (int k = 0; k < HID; ++k) s = fmaf(bg[k], Lg[k * HID + cc], s);
            gCB[tid] = s;
        }
        if (tid <= NT) {
            float m = att[0];
            for (int t = 1; t < NT; ++t) m = fmaxf(m, att[t]);
            float tot = 0.f, pre = 0.f;
            for (int t = 0; t < NT; ++t) {
                const float e = __expf(att[t] - m);
                tot += e;
                if (t < tid) pre += e;
            }
            gPC[tid] = pre / tot;
        }
    }
}

// ---- main: grid 256 (block = 2 batches), 512 threads, 2 barriers ------------
__global__ __launch_bounds__(512, 4)
void a3_main(const int* __restrict__ xbg, const int* __restrict__ LOSb,
             const float* __restrict__ Wc1, const float* __restrict__ bc1,
             const float* __restrict__ Wc2, const float* __restrict__ bc2,
             float* __restrict__ out) {
    __shared__ float sA[NND][NND];          // 4 KB
    __shared__ float scb[2][HID];           // 512 B
    __shared__ float part[2][8][HID];       // 4 KB
    __shared__ float spool[2][HID];

    const int b0   = blockIdx.x * 2;
    const int tid  = threadIdx.x;
    const int hd   = tid & 63;
    const int wv   = tid >> 6;              // 0..7
    const int var  = wv >> 2;               // 0: ad, 1: dis
    const int n0   = (wv & 3) * 8;

    // stage: adjacency + cb (one barrier)
#pragma unroll
    for (int i = 0; i < 2; ++i) ((float*)sA)[tid + 512 * i] = gA[tid + 512 * i];
    if (tid < 2 * HID) ((float*)scb)[tid] = gCB[tid];
    // per-lane vocab indices for this wave's variant, both batches
    const int xv0 = xbg[b0 * CCH + var * NND + (tid & 31)];
    const int xv1 = xbg[(b0 + 1) * CCH + var * NND + (tid & 31)];
    const float cA0 = gPC[LOSb[b0]];
    const float cA1 = gPC[LOSb[b0 + 1]];
    __syncthreads();

    // gate loops, both batches sequentially
#pragma unroll
    for (int bi = 0; bi < 2; ++bi) {
        const int   xv = bi ? xv1 : xv0;
        const float cA = bi ? cA1 : cA0;
        float zacc[8], hacc[8];
#pragma unroll
        for (int j = 0; j < 8; ++j) { zacc[j] = 0.f; hacc[j] = 0.f; }
#pragma unroll 8
        for (int q = 0; q < NND; ++q) {
            const int xq = __shfl(xv, q);                       // vocab id of channel
            const int cc = var * NND + q;
            const float2 t = gT2[(cc * VOC + xq) * HID + hd];   // coalesced, L2-hot
#pragma unroll
            for (int j = 0; j < 8; ++j) {
                const float a = sA[n0 + j][q];                  // broadcast
                zacc[j] = fmaf(a, t.x, zacc[j]);
                hacc[j] = fmaf(a, t.y, hacc[j]);
            }
        }
        const float wr = var ? (1.0f - cA) : cA;
        float psum = 0.f;
#pragma unroll
        for (int j = 0; j < 8; ++j) {
            const float zl = zacc[j] + scb[0][hd];
            const float hl = hacc[j] + scb[1][hd];
            const float Z  = 1.0f / (1.0f + __expf(-zl));
            const float e2 = __expf(2.0f * hl);
            const float Ht = (e2 - 1.0f) / (e2 + 1.0f);
            psum = fmaf(1.0f - Z, Ht, psum);
        }
        part[bi][wv][hd] = wr * psum;
    }
    __syncthreads();                         // second (last) barrier

    // tail: wave 0 -> batch b0, wave 1 -> batch b0+1; other waves done
    if (wv < 2) {
        const int bi = wv;
        float s = 0.f;
#pragma unroll
        for (int g = 0; g < 8; ++g) s += part[bi][g][hd];
        spool[bi][hd] = s * (1.0f / NND);    // wave-internal LDS, no barrier
        float a0 = bc1[hd], a1 = bc1[hd + 64];
#pragma unroll 8
        for (int k = 0; k < HID; ++k) {
            const float pk = spool[bi][k];
            a0 = fmaf(pk, Wc1[k * 2 * HID + hd], a0);
            a1 = fmaf(pk, Wc1[k * 2 * HID + hd + 64], a1);
        }
        float v = fmaxf(a0, 0.f) * Wc2[hd] + fmaxf(a1, 0.f) * Wc2[hd + 64];
#pragma unroll
        for (int off = 32; off; off >>= 1) v += __shfl_down(v, off);
        if (hd == 0) out[b0 + bi] = v + bc2[0];
    }
}

extern "C" void kernel_launch(void* const* d_in, const int* in_sizes, int n_in,
                              void* d_out, int out_size, void* d_ws, size_t ws_size,
                              hipStream_t stream) {
    const int*   x_batch = (const int*)d_in[0];
    const int*   LOSb    = (const int*)d_in[1];
    const int*   tei     = (const int*)d_in[2];
    const float* emb     = (const float*)d_in[3];
    const float* Wz      = (const float*)d_in[4];
    const float* bz      = (const float*)d_in[5];
    const float* Wh      = (const float*)d_in[8];
    const float* bh      = (const float*)d_in[9];
    const float* Lz      = (const float*)d_in[10];
    const float* lbz     = (const float*)d_in[11];
    const float* Lh      = (const float*)d_in[14];
    const float* lbh     = (const float*)d_in[15];
    const float* att     = (const float*)d_in[16];
    const float* Wc1     = (const float*)d_in[17];
    const float* bc1     = (const float*)d_in[18];
    const float* Wc2     = (const float*)d_in[19];
    const float* bc2     = (const float*)d_in[20];
    float* outp = (float*)d_out;

    hipLaunchKernelGGL(a3_prep, dim3(256), dim3(512), 0, stream,
                       tei, att, emb, Wz, bz, Wh, bh, Lz, lbz, Lh, lbh);
    hipLaunchKernelGGL(a3_main, dim3(BATCH / 2), dim3(512), 0, stream,
                       x_batch, LOSb, Wc1, bc1, Wc2, bc2, outp);
}